// Round 9
// baseline (602.897 us; speedup 1.0000x reference)
//
#include <hip/hip_runtime.h>
#include <hip/hip_bf16.h>
#include <hip/hip_fp16.h>

#define NNODES 50000
#define NEDGES 600000
#define DIM    128
#define NLAYERS 3
#define NCLS   10
#define NGRAPH 256
#define BN_EPS 1e-5f

#define SCAN_BLK 256
#define NSB ((NNODES + SCAN_BLK - 1) / SCAN_BLK)   // 196 blocks
#define NBINS 64

typedef __attribute__((ext_vector_type(8))) short bf16x8;   // 8 bf16 = 4 VGPR
typedef __attribute__((ext_vector_type(4))) float f32x4;

static __device__ __forceinline__ unsigned short f2b(float f) {
    union { __hip_bfloat16 h; unsigned short u; } c;
    c.h = __float2bfloat16(f);
    return c.u;
}
static __device__ __forceinline__ float b2f(short s) {
    return __uint_as_float(((unsigned)(unsigned short)s) << 16);
}
static __device__ __forceinline__ unsigned pack2(float a, float b) {
    return (unsigned)f2b(a) | ((unsigned)f2b(b) << 16);
}

// ---------------- workspace zeroing ----------------
__global__ __launch_bounds__(256) void zero_bufs(int4* __restrict__ a, int na,
                                                 int4* __restrict__ b, int nb,
                                                 int4* __restrict__ c, int nc) {
    int i = blockIdx.x * 256 + threadIdx.x;
    int4 z = make_int4(0, 0, 0, 0);
    if (i < na) a[i] = z;
    if (i < nb) b[i] = z;
    if (i < nc) c[i] = z;
}

// ---------------- CSR build ----------------

__global__ void count_deg(const int* __restrict__ dst, int* __restrict__ deg, int E) {
    int e = blockIdx.x * blockDim.x + threadIdx.x;
    if (e < E) atomicAdd(&deg[dst[e]], 1);
}

__global__ __launch_bounds__(SCAN_BLK) void partial_sum(const int* __restrict__ deg,
                                                        int* __restrict__ part, int n) {
    int t = threadIdx.x;
    int i = blockIdx.x * SCAN_BLK + t;
    int v = (i < n) ? deg[i] : 0;
#pragma unroll
    for (int o = 32; o > 0; o >>= 1) v += __shfl_down(v, o, 64);
    __shared__ int s[SCAN_BLK / 64];
    if ((t & 63) == 0) s[t >> 6] = v;
    __syncthreads();
    if (t == 0) {
        int sum = 0;
#pragma unroll
        for (int w = 0; w < SCAN_BLK / 64; ++w) sum += s[w];
        part[blockIdx.x] = sum;
    }
}

__global__ __launch_bounds__(256) void scan_partials(int* __restrict__ part, int nb) {
    __shared__ int s[256];
    int t = threadIdx.x;
    int v = (t < nb) ? part[t] : 0;
    s[t] = v;
    __syncthreads();
    for (int o = 1; o < 256; o <<= 1) {
        int u = (t >= o) ? s[t - o] : 0;
        __syncthreads();
        s[t] += u;
        __syncthreads();
    }
    if (t < nb) part[t] = (t == 0) ? 0 : s[t - 1];
}

__global__ __launch_bounds__(SCAN_BLK) void emit_offsets(const int* __restrict__ deg,
                                                         const int* __restrict__ part,
                                                         int* __restrict__ off,
                                                         int* __restrict__ cursor, int n) {
    __shared__ int s[SCAN_BLK];
    int t = threadIdx.x;
    int i = blockIdx.x * SCAN_BLK + t;
    int v = (i < n) ? deg[i] : 0;
    s[t] = v;
    __syncthreads();
    for (int o = 1; o < SCAN_BLK; o <<= 1) {
        int u = (t >= o) ? s[t - o] : 0;
        __syncthreads();
        s[t] += u;
        __syncthreads();
    }
    if (i < n) {
        int excl = part[blockIdx.x] + s[t] - v;
        off[i] = excl;
        cursor[i] = excl;
    }
}

// 4B per edge: low16 = src (N<65536), high16 = weight as f16.
__global__ void fill_csr(const int* __restrict__ src, const int* __restrict__ dst,
                         const float* __restrict__ emask,
                         int* __restrict__ cursor,
                         unsigned* __restrict__ csr4, int E) {
    int e = blockIdx.x * blockDim.x + threadIdx.x;
    if (e < E) {
        int d = dst[e];
        int p = atomicAdd(&cursor[d], 1);
        unsigned wbits = (unsigned)__half_as_ushort(__float2half(emask[e]));
        csr4[p] = (unsigned)src[e] | (wbits << 16);
    }
}

// ---------------- degree-balanced permutation (counting sort, 64 bins) ----------------
// Nodes sorted by degree -> quarter-wave node groups have near-equal degree ->
// gather loop runs ~deg iterations instead of max-of-4 (~25% masked waste removed).

__global__ void hist_deg(const int* __restrict__ deg, int* __restrict__ hist, int n) {
    int i = blockIdx.x * blockDim.x + threadIdx.x;
    if (i < n) {
        int b = deg[i]; if (b > NBINS - 1) b = NBINS - 1;
        atomicAdd(&hist[b], 1);
    }
}

__global__ __launch_bounds__(64) void scan_hist(const int* __restrict__ hist,
                                                int* __restrict__ binCur) {
    __shared__ int s[NBINS];
    int t = threadIdx.x;
    s[t] = hist[t];
    __syncthreads();
    if (t == 0) {
        int run = 0;
        for (int i = 0; i < NBINS; ++i) { int v = s[i]; s[i] = run; run += v; }
    }
    __syncthreads();
    binCur[t] = s[t];
}

__global__ void place_perm(const int* __restrict__ deg, int* __restrict__ binCur,
                           int* __restrict__ perm, int n) {
    int i = blockIdx.x * blockDim.x + threadIdx.x;
    if (i < n) {
        int b = deg[i]; if (b > NBINS - 1) b = NBINS - 1;
        int p = atomicAdd(&binCur[b], 1);
        perm[p] = i;
    }
}

// ---------------- prep: BN fold, W transpose->bf16, x->bf16 ----------------

__global__ void prep_bn(const float* __restrict__ gamma, const float* __restrict__ beta,
                        const float* __restrict__ mean, const float* __restrict__ var,
                        const float* __restrict__ b1,
                        float* __restrict__ colA, float* __restrict__ colB, int n) {
    int i = blockIdx.x * blockDim.x + threadIdx.x;
    if (i < n) {
        float A = gamma[i] * rsqrtf(var[i] + BN_EPS);
        colA[i] = A;
        colB[i] = beta[i] - mean[i] * A + b1[i] * A;
    }
}

// W[l][k][n] f32  ->  WT[l][n][k] bf16
__global__ void prep_wt(const float* __restrict__ W1, const float* __restrict__ W2,
                        unsigned short* __restrict__ W1T, unsigned short* __restrict__ W2T, int total) {
    int i = blockIdx.x * blockDim.x + threadIdx.x;
    if (i < total) {
        int l  = i / (DIM * DIM);
        int r  = i - l * DIM * DIM;
        int nn = r / DIM;
        int kk = r - nn * DIM;
        int sidx = l * DIM * DIM + kk * DIM + nn;
        W1T[i] = f2b(W1[sidx]);
        W2T[i] = f2b(W2[sidx]);
    }
}

__global__ void conv_x(const float* __restrict__ x, unsigned short* __restrict__ xb, int n4) {
    int i = blockIdx.x * blockDim.x + threadIdx.x;
    if (i < n4) {
        float4 v = ((const float4*)x)[i];
        unsigned lo = pack2(v.x, v.y);
        unsigned hi = pack2(v.z, v.w);
        ((uint2*)xb)[i] = make_uint2(lo, hi);
    }
}

// ---------------- gather0: weighted SimpleConv + supernode select (perm'd) ----------------
// 4 nodes/wave (degree-matched via perm), 16 lanes/node, 16B chunks, 8x unrolled.

__global__ __launch_bounds__(256) void gather0(const unsigned short* __restrict__ xb,
                                               const int* __restrict__ off, const int* __restrict__ deg,
                                               const unsigned* __restrict__ csr4,
                                               const int* __restrict__ snmask,
                                               const int* __restrict__ perm,
                                               unsigned short* __restrict__ X, int n) {
    int wave = (blockIdx.x * blockDim.x + threadIdx.x) >> 6;
    int lane = threadIdx.x & 63;
    int q    = lane >> 4;
    int l16  = lane & 15;
    int idx  = wave * 4 + q;
    bool valid = idx < n;
    int node = perm[valid ? idx : (n - 1)];
    int base = off[node];
    int dg   = valid ? deg[node] : 0;

    float acc[8];
#pragma unroll
    for (int i = 0; i < 8; ++i) acc[i] = 0.f;

    int j = 0;
    for (; j + 8 <= dg; j += 8) {
        unsigned cc[8];
#pragma unroll
        for (int u = 0; u < 8; ++u) cc[u] = csr4[base + j + u];
        bf16x8 vv[8];
#pragma unroll
        for (int u = 0; u < 8; ++u)
            vv[u] = *(const bf16x8*)&xb[(long)(cc[u] & 0xffffu) * DIM + l16 * 8];
#pragma unroll
        for (int u = 0; u < 8; ++u) {
            float w = __half2float(__ushort_as_half((unsigned short)(cc[u] >> 16)));
#pragma unroll
            for (int i = 0; i < 8; ++i) acc[i] = fmaf(w, b2f(vv[u][i]), acc[i]);
        }
    }
    for (; j + 4 <= dg; j += 4) {
        unsigned cc[4];
#pragma unroll
        for (int u = 0; u < 4; ++u) cc[u] = csr4[base + j + u];
        bf16x8 vv[4];
#pragma unroll
        for (int u = 0; u < 4; ++u)
            vv[u] = *(const bf16x8*)&xb[(long)(cc[u] & 0xffffu) * DIM + l16 * 8];
#pragma unroll
        for (int u = 0; u < 4; ++u) {
            float w = __half2float(__ushort_as_half((unsigned short)(cc[u] >> 16)));
#pragma unroll
            for (int i = 0; i < 8; ++i) acc[i] = fmaf(w, b2f(vv[u][i]), acc[i]);
        }
    }
    for (; j < dg; ++j) {
        unsigned c = csr4[base + j];
        float w = __half2float(__ushort_as_half((unsigned short)(c >> 16)));
        bf16x8 v = *(const bf16x8*)&xb[(long)(c & 0xffffu) * DIM + l16 * 8];
#pragma unroll
        for (int i = 0; i < 8; ++i) acc[i] = fmaf(w, b2f(v[i]), acc[i]);
    }

    if (valid) {
        bf16x8 res = *(const bf16x8*)&xb[(long)node * DIM + l16 * 8];  // self
        if (snmask[node]) {
#pragma unroll
            for (int i = 0; i < 8; ++i) res[i] = (short)f2b(acc[i]);
        }
        *(bf16x8*)&X[(long)node * DIM + l16 * 8] = res;
    }
}

// ---------------- fused GIN layer: gather(LDS) -> Lin1+BN+ReLU -> Lin2+ReLU ----------------
// 512 threads = 8 waves, 64 (perm'd) rows/block. Results are row-independent, so the
// permutation only changes scheduling; write-out scatters whole 256B rows to Xout[perm[.]].
#define HPITCH 136   // bf16 elems; 272B rows: 16B-aligned, 2-way LDS aliasing only

__global__ __launch_bounds__(512) void gin_layer(const unsigned short* __restrict__ Xin,
                                                 unsigned short* __restrict__ Xout,
                                                 const int* __restrict__ off, const int* __restrict__ deg,
                                                 const unsigned* __restrict__ csr4,
                                                 const int* __restrict__ perm,
                                                 const unsigned short* __restrict__ W1T,
                                                 const unsigned short* __restrict__ W2T,
                                                 const float* __restrict__ colA, const float* __restrict__ colB,
                                                 const float* __restrict__ b2, int n) {
    __shared__ unsigned short h_in[64 * HPITCH];
    __shared__ unsigned short h_t[64 * HPITCH];
    int t    = threadIdx.x;
    int wid  = t >> 6;
    int lane = t & 63;
    int q    = lane >> 4;
    int l16  = lane & 15;
    int lm   = lane & 15;
    int lk   = (lane >> 4) * 8;
    int wr   = wid >> 2;          // 0..1
    int wc   = wid & 3;           // 0..3
    int c0   = wc * 32;
    int row0 = blockIdx.x * 64;

    // ---- W1 B-fragments first: weight fetch overlaps gather latency ----
    bf16x8 b1[2][4];
#pragma unroll
    for (int cs = 0; cs < 2; ++cs)
#pragma unroll
        for (int ks = 0; ks < 4; ++ks) {
            int col = c0 + cs * 16 + lm;
            b1[cs][ks] = *(const bf16x8*)&W1T[col * DIM + ks * 32 + lk];
        }

    // ---- gather phase: GIN eps=0 agg into h_in (degree-matched quarter-waves) ----
#pragma unroll
    for (int rnd = 0; rnd < 2; ++rnd) {
        int lrow = wid * 8 + rnd * 4 + q;
        int idx  = row0 + lrow;
        bool valid = idx < n;
        int node = perm[valid ? idx : (n - 1)];
        int base = off[node];
        int dg   = valid ? deg[node] : 0;

        float acc[8];
        {
            bf16x8 self = *(const bf16x8*)&Xin[(long)node * DIM + l16 * 8];
#pragma unroll
            for (int i = 0; i < 8; ++i) acc[i] = b2f(self[i]);
        }
        int j = 0;
        for (; j + 8 <= dg; j += 8) {
            unsigned ee[8];
#pragma unroll
            for (int u = 0; u < 8; ++u) ee[u] = csr4[base + j + u];
            bf16x8 vv[8];
#pragma unroll
            for (int u = 0; u < 8; ++u)
                vv[u] = *(const bf16x8*)&Xin[(long)(ee[u] & 0xffffu) * DIM + l16 * 8];
#pragma unroll
            for (int u = 0; u < 8; ++u)
#pragma unroll
                for (int i = 0; i < 8; ++i) acc[i] += b2f(vv[u][i]);
        }
        for (; j + 4 <= dg; j += 4) {
            unsigned ee[4];
#pragma unroll
            for (int u = 0; u < 4; ++u) ee[u] = csr4[base + j + u];
            bf16x8 vv[4];
#pragma unroll
            for (int u = 0; u < 4; ++u)
                vv[u] = *(const bf16x8*)&Xin[(long)(ee[u] & 0xffffu) * DIM + l16 * 8];
#pragma unroll
            for (int u = 0; u < 4; ++u)
#pragma unroll
                for (int i = 0; i < 8; ++i) acc[i] += b2f(vv[u][i]);
        }
        for (; j < dg; ++j) {
            unsigned e = csr4[base + j];
            bf16x8 v = *(const bf16x8*)&Xin[(long)(e & 0xffffu) * DIM + l16 * 8];
#pragma unroll
            for (int i = 0; i < 8; ++i) acc[i] += b2f(v[i]);
        }
        bf16x8 r;
#pragma unroll
        for (int i = 0; i < 8; ++i) r[i] = valid ? (short)f2b(acc[i]) : (short)0;
        *(bf16x8*)&h_in[lrow * HPITCH + l16 * 8] = r;
    }
    __syncthreads();

    // ---- GEMM1 ----
    bf16x8 a[2][4];
#pragma unroll
    for (int rs = 0; rs < 2; ++rs)
#pragma unroll
        for (int ks = 0; ks < 4; ++ks)
            a[rs][ks] = *(const bf16x8*)&h_in[(wr * 32 + rs * 16 + lm) * HPITCH + ks * 32 + lk];

    f32x4 acc[2][2];
    f32x4 z = {0.f, 0.f, 0.f, 0.f};
#pragma unroll
    for (int rs = 0; rs < 2; ++rs)
#pragma unroll
        for (int cs = 0; cs < 2; ++cs) acc[rs][cs] = z;

#pragma unroll
    for (int ks = 0; ks < 4; ++ks)
#pragma unroll
        for (int rs = 0; rs < 2; ++rs)
#pragma unroll
            for (int cs = 0; cs < 2; ++cs)
                acc[rs][cs] = __builtin_amdgcn_mfma_f32_16x16x32_bf16(a[rs][ks], b1[cs][ks], acc[rs][cs], 0, 0, 0);

    // ---- epilogue 1: affine(BN)+ReLU -> h_t ----
#pragma unroll
    for (int rs = 0; rs < 2; ++rs)
#pragma unroll
        for (int cs = 0; cs < 2; ++cs) {
            int colv = c0 + cs * 16 + lm;
            float cA = colA[colv], cB = colB[colv];
            int rbase = wr * 32 + rs * 16 + (lane >> 4) * 4;
            f32x4 av = acc[rs][cs];
#pragma unroll
            for (int v = 0; v < 4; ++v) {
                float h = fmaxf(fmaf(av[v], cA, cB), 0.f);
                h_t[(rbase + v) * HPITCH + colv] = f2b(h);
            }
        }
    __syncthreads();

    // ---- GEMM2 ----
    bf16x8 a2[2][4];
#pragma unroll
    for (int rs = 0; rs < 2; ++rs)
#pragma unroll
        for (int ks = 0; ks < 4; ++ks)
            a2[rs][ks] = *(const bf16x8*)&h_t[(wr * 32 + rs * 16 + lm) * HPITCH + ks * 32 + lk];

    bf16x8 b2f_[2][4];
#pragma unroll
    for (int cs = 0; cs < 2; ++cs)
#pragma unroll
        for (int ks = 0; ks < 4; ++ks) {
            int col = c0 + cs * 16 + lm;
            b2f_[cs][ks] = *(const bf16x8*)&W2T[col * DIM + ks * 32 + lk];
        }

#pragma unroll
    for (int rs = 0; rs < 2; ++rs)
#pragma unroll
        for (int cs = 0; cs < 2; ++cs) acc[rs][cs] = z;

#pragma unroll
    for (int ks = 0; ks < 4; ++ks)
#pragma unroll
        for (int rs = 0; rs < 2; ++rs)
#pragma unroll
            for (int cs = 0; cs < 2; ++cs)
                acc[rs][cs] = __builtin_amdgcn_mfma_f32_16x16x32_bf16(a2[rs][ks], b2f_[cs][ks], acc[rs][cs], 0, 0, 0);

    __syncthreads();

    // ---- epilogue 2: +bias, ReLU -> h_t ----
#pragma unroll
    for (int rs = 0; rs < 2; ++rs)
#pragma unroll
        for (int cs = 0; cs < 2; ++cs) {
            int colv = c0 + cs * 16 + lm;
            float bb = b2[colv];
            int rbase = wr * 32 + rs * 16 + (lane >> 4) * 4;
            f32x4 av = acc[rs][cs];
#pragma unroll
            for (int v = 0; v < 4; ++v) {
                float h = fmaxf(av[v] + bb, 0.f);
                h_t[(rbase + v) * HPITCH + colv] = f2b(h);
            }
        }
    __syncthreads();

    // ---- copy-out: 64 rows scattered to Xout[perm[.]], 32B per thread within row ----
    {
        int row = t >> 3;
        int ch  = (t & 7) * 16;
        int gr  = row0 + row;
        if (gr < n) {
            int node = perm[gr];
            *(bf16x8*)&Xout[(long)node * DIM + ch]     = *(const bf16x8*)&h_t[row * HPITCH + ch];
            *(bf16x8*)&Xout[(long)node * DIM + ch + 8] = *(const bf16x8*)&h_t[row * HPITCH + ch + 8];
        }
    }
}

// ---------------- pool (batch sorted -> run-accumulate) ----------------

__global__ __launch_bounds__(128) void pool_kernel(const unsigned short* __restrict__ X,
                                                   const int* __restrict__ batch,
                                                   float* __restrict__ POOL, int n) {
    int c  = threadIdx.x;
    int n0 = blockIdx.x * 128;
    if (n0 >= n) return;
    int n1 = n0 + 128; if (n1 > n) n1 = n;
    int gcur = batch[n0];
    float acc = 0.f;
    for (int i = n0; i < n1; ++i) {
        int g = batch[i];
        if (g != gcur) {
            atomicAdd(&POOL[(long)gcur * DIM + c], acc);
            acc = 0.f; gcur = g;
        }
        acc += __uint_as_float(((unsigned)X[(long)i * DIM + c]) << 16);
    }
    atomicAdd(&POOL[(long)gcur * DIM + c], acc);
}

// ---------------- final head ----------------

__global__ __launch_bounds__(128) void final_mlp(const float* __restrict__ POOL,
                                                 const float* __restrict__ Wf1, const float* __restrict__ bf1,
                                                 const float* __restrict__ Wf2, const float* __restrict__ bf2,
                                                 float* __restrict__ out) {
    int g = blockIdx.x;
    int t = threadIdx.x;
    __shared__ float p[128];
    __shared__ float h[128];
    p[t] = POOL[(long)g * DIM + t];
    __syncthreads();
    float acc = bf1[t];
#pragma unroll 8
    for (int k = 0; k < DIM; ++k) acc = fmaf(p[k], Wf1[k * DIM + t], acc);
    h[t] = fmaxf(acc, 0.f);
    __syncthreads();
    if (t < NCLS) {
        float acc2 = bf2[t];
#pragma unroll 8
        for (int k = 0; k < DIM; ++k) acc2 = fmaf(h[k], Wf2[k * NCLS + t], acc2);
        out[(long)g * NCLS + t] = acc2;
    }
}

// ---------------- launch ----------------

extern "C" void kernel_launch(void* const* d_in, const int* in_sizes, int n_in,
                              void* d_out, int out_size, void* d_ws, size_t ws_size,
                              hipStream_t stream) {
    const float* x      = (const float*)d_in[0];
    const int*   ei     = (const int*)d_in[1];
    const int*   snmask = (const int*)d_in[2];
    const float* emask  = (const float*)d_in[3];
    const int*   batch  = (const int*)d_in[4];
    const float* Ws1    = (const float*)d_in[5];
    const float* bs1    = (const float*)d_in[6];
    const float* gamma  = (const float*)d_in[7];
    const float* beta   = (const float*)d_in[8];
    const float* mean   = (const float*)d_in[9];
    const float* var    = (const float*)d_in[10];
    const float* Ws2    = (const float*)d_in[11];
    const float* bs2    = (const float*)d_in[12];
    const float* Wf1    = (const float*)d_in[13];
    const float* bf1    = (const float*)d_in[14];
    const float* Wf2    = (const float*)d_in[15];
    const float* bf2    = (const float*)d_in[16];
    float* out = (float*)d_out;

    const int* srcp = ei;
    const int* dstp = ei + NEDGES;

    char* ws = (char*)d_ws;
    size_t o = 0;
    auto alloc = [&](size_t bytes) -> void* {
        void* p = ws + o;
        o = (o + bytes + 255) & ~(size_t)255;
        return p;
    };
    unsigned short* XB  = (unsigned short*)alloc((size_t)NNODES * DIM * 2);
    unsigned short* X   = (unsigned short*)alloc((size_t)NNODES * DIM * 2);
    unsigned short* H   = (unsigned short*)alloc((size_t)NNODES * DIM * 2);
    int*   deg     = (int*)alloc((size_t)NNODES * 4);
    int*   off     = (int*)alloc((size_t)NNODES * 4);
    int*   cursor  = (int*)alloc((size_t)NNODES * 4);
    int*   part    = (int*)alloc((size_t)NSB * 4);
    unsigned* csr4 = (unsigned*)alloc((size_t)NEDGES * 4);
    int*   histcur = (int*)alloc((size_t)2 * NBINS * 4);   // hist | binCur
    int*   perm    = (int*)alloc((size_t)NNODES * 4);
    float* colA    = (float*)alloc((size_t)NLAYERS * DIM * 4);
    float* colB    = (float*)alloc((size_t)NLAYERS * DIM * 4);
    unsigned short* W1T = (unsigned short*)alloc((size_t)NLAYERS * DIM * DIM * 2);
    unsigned short* W2T = (unsigned short*)alloc((size_t)NLAYERS * DIM * DIM * 2);
    float* POOL    = (float*)alloc((size_t)NGRAPH * DIM * 4);

    int* hist   = histcur;
    int* binCur = histcur + NBINS;

    // deg: 12500 int4; POOL: 8192 int4; hist+binCur: 32 int4
    zero_bufs<<<(12500 + 255) / 256, 256, 0, stream>>>((int4*)deg, 12500, (int4*)POOL, 8192,
                                                       (int4*)histcur, 32);

    count_deg<<<(NEDGES + 255) / 256, 256, 0, stream>>>(dstp, deg, NEDGES);
    partial_sum<<<NSB, SCAN_BLK, 0, stream>>>(deg, part, NNODES);
    scan_partials<<<1, 256, 0, stream>>>(part, NSB);
    emit_offsets<<<NSB, SCAN_BLK, 0, stream>>>(deg, part, off, cursor, NNODES);
    fill_csr<<<(NEDGES + 255) / 256, 256, 0, stream>>>(srcp, dstp, emask, cursor, csr4, NEDGES);
    hist_deg<<<(NNODES + 255) / 256, 256, 0, stream>>>(deg, hist, NNODES);
    scan_hist<<<1, NBINS, 0, stream>>>(hist, binCur);
    place_perm<<<(NNODES + 255) / 256, 256, 0, stream>>>(deg, binCur, perm, NNODES);
    prep_bn<<<(NLAYERS * DIM + 255) / 256, 256, 0, stream>>>(gamma, beta, mean, var, bs1, colA, colB, NLAYERS * DIM);
    prep_wt<<<(NLAYERS * DIM * DIM + 255) / 256, 256, 0, stream>>>(Ws1, Ws2, W1T, W2T, NLAYERS * DIM * DIM);
    conv_x<<<(NNODES * DIM / 4 + 255) / 256, 256, 0, stream>>>(x, XB, NNODES * DIM / 4);

    const int nWaves = (NNODES + 3) / 4;
    const int gatherBlocks = (nWaves * 64 + 255) / 256;
    gather0<<<gatherBlocks, 256, 0, stream>>>(XB, off, deg, csr4, snmask, perm, X, NNODES);

    // ping-pong: X -> H -> X -> H
    const unsigned short* bufs[4] = {X, H, X, H};
    const int layerBlocks = (NNODES + 63) / 64;
    for (int l = 0; l < NLAYERS; ++l) {
        gin_layer<<<layerBlocks, 512, 0, stream>>>((const unsigned short*)bufs[l],
                                                   (unsigned short*)bufs[l + 1],
                                                   off, deg, csr4, perm,
                                                   W1T + (size_t)l * DIM * DIM,
                                                   W2T + (size_t)l * DIM * DIM,
                                                   colA + (size_t)l * DIM,
                                                   colB + (size_t)l * DIM,
                                                   bs2 + (size_t)l * DIM, NNODES);
    }

    pool_kernel<<<(NNODES + 127) / 128, 128, 0, stream>>>(H, batch, POOL, NNODES);
    final_mlp<<<NGRAPH, 128, 0, stream>>>(POOL, Wf1, bf1, Wf2, bf2, out);
}

// Round 10
// 297.167 us; speedup vs baseline: 2.0288x; 2.0288x over previous
//
#include <hip/hip_runtime.h>
#include <hip/hip_bf16.h>
#include <hip/hip_fp16.h>

#define NNODES 50000
#define NEDGES 600000
#define DIM    128
#define NLAYERS 3
#define NCLS   10
#define NGRAPH 256
#define BN_EPS 1e-5f

#define SCAN_BLK 256
#define NSB ((NNODES + SCAN_BLK - 1) / SCAN_BLK)   // 196 blocks
#define NBINS 64

typedef __attribute__((ext_vector_type(8))) short bf16x8;   // 8 bf16 = 4 VGPR
typedef __attribute__((ext_vector_type(4))) float f32x4;

static __device__ __forceinline__ unsigned short f2b(float f) {
    union { __hip_bfloat16 h; unsigned short u; } c;
    c.h = __float2bfloat16(f);
    return c.u;
}
static __device__ __forceinline__ float b2f(short s) {
    return __uint_as_float(((unsigned)(unsigned short)s) << 16);
}
static __device__ __forceinline__ unsigned pack2(float a, float b) {
    return (unsigned)f2b(a) | ((unsigned)f2b(b) << 16);
}

// ---------------- workspace zeroing ----------------
__global__ __launch_bounds__(256) void zero_bufs(int4* __restrict__ a, int na,
                                                 int4* __restrict__ b, int nb) {
    int i = blockIdx.x * 256 + threadIdx.x;
    int4 z = make_int4(0, 0, 0, 0);
    if (i < na) a[i] = z;
    if (i < nb) b[i] = z;
}

// ---------------- CSR build ----------------

__global__ void count_deg(const int* __restrict__ dst, int* __restrict__ deg, int E) {
    int e = blockIdx.x * blockDim.x + threadIdx.x;
    if (e < E) atomicAdd(&deg[dst[e]], 1);
}

__global__ __launch_bounds__(SCAN_BLK) void partial_sum(const int* __restrict__ deg,
                                                        int* __restrict__ part, int n) {
    int t = threadIdx.x;
    int i = blockIdx.x * SCAN_BLK + t;
    int v = (i < n) ? deg[i] : 0;
#pragma unroll
    for (int o = 32; o > 0; o >>= 1) v += __shfl_down(v, o, 64);
    __shared__ int s[SCAN_BLK / 64];
    if ((t & 63) == 0) s[t >> 6] = v;
    __syncthreads();
    if (t == 0) {
        int sum = 0;
#pragma unroll
        for (int w = 0; w < SCAN_BLK / 64; ++w) sum += s[w];
        part[blockIdx.x] = sum;
    }
}

__global__ __launch_bounds__(256) void scan_partials(int* __restrict__ part, int nb) {
    __shared__ int s[256];
    int t = threadIdx.x;
    int v = (t < nb) ? part[t] : 0;
    s[t] = v;
    __syncthreads();
    for (int o = 1; o < 256; o <<= 1) {
        int u = (t >= o) ? s[t - o] : 0;
        __syncthreads();
        s[t] += u;
        __syncthreads();
    }
    if (t < nb) part[t] = (t == 0) ? 0 : s[t - 1];
}

__global__ __launch_bounds__(SCAN_BLK) void emit_offsets(const int* __restrict__ deg,
                                                         const int* __restrict__ part,
                                                         int* __restrict__ off,
                                                         int* __restrict__ cursor, int n) {
    __shared__ int s[SCAN_BLK];
    int t = threadIdx.x;
    int i = blockIdx.x * SCAN_BLK + t;
    int v = (i < n) ? deg[i] : 0;
    s[t] = v;
    __syncthreads();
    for (int o = 1; o < SCAN_BLK; o <<= 1) {
        int u = (t >= o) ? s[t - o] : 0;
        __syncthreads();
        s[t] += u;
        __syncthreads();
    }
    if (i < n) {
        int excl = part[blockIdx.x] + s[t] - v;
        off[i] = excl;
        cursor[i] = excl;
    }
}

// 4B per edge: low16 = src (N<65536), high16 = weight as f16.
__global__ void fill_csr(const int* __restrict__ src, const int* __restrict__ dst,
                         const float* __restrict__ emask,
                         int* __restrict__ cursor,
                         unsigned* __restrict__ csr4, int E) {
    int e = blockIdx.x * blockDim.x + threadIdx.x;
    if (e < E) {
        int d = dst[e];
        int p = atomicAdd(&cursor[d], 1);
        unsigned wbits = (unsigned)__half_as_ushort(__float2half(emask[e]));
        csr4[p] = (unsigned)src[e] | (wbits << 16);
    }
}

// ---------------- degree-balanced permutation: contention-free counting sort ----------------
// Round-9 lesson: 50K global atomics on 64 bins serialize (~200ns each) -> 157us.
// Now: per-block LDS histograms -> [bin][block] matrix scan -> LDS-rank placement.

__global__ __launch_bounds__(256) void hist_block(const int* __restrict__ deg,
                                                  int* __restrict__ blockHist, int n) {
    __shared__ int h[NBINS];
    int t = threadIdx.x;
    if (t < NBINS) h[t] = 0;
    __syncthreads();
    int i = blockIdx.x * 256 + t;
    if (i < n) {
        int b = deg[i]; if (b > NBINS - 1) b = NBINS - 1;
        atomicAdd(&h[b], 1);       // LDS atomic, ~4-way contention
    }
    __syncthreads();
    if (t < NBINS) blockHist[t * NSB + blockIdx.x] = h[t];   // bin-major
}

// exclusive scan of the 64x196 = 12544-entry matrix (L2-hot), one 1024-thread block
__global__ __launch_bounds__(1024) void scan_matrix(int* __restrict__ m, int total) {
    __shared__ int s[1024];
    int t = threadIdx.x;
    const int CH = (total + 1023) / 1024;   // 13
    int lo = t * CH;
    int hi = lo + CH; if (hi > total) hi = total;
    int sum = 0;
    for (int i = lo; i < hi; ++i) sum += m[i];
    s[t] = sum;
    __syncthreads();
    for (int o = 1; o < 1024; o <<= 1) {
        int v = (t >= o) ? s[t - o] : 0;
        __syncthreads();
        s[t] += v;
        __syncthreads();
    }
    int run = (t == 0) ? 0 : s[t - 1];
    for (int i = lo; i < hi; ++i) {
        int v = m[i]; m[i] = run; run += v;
    }
}

__global__ __launch_bounds__(256) void place_block(const int* __restrict__ deg,
                                                   const int* __restrict__ blockHist,
                                                   int* __restrict__ perm, int n) {
    __shared__ int h[NBINS];
    int t = threadIdx.x;
    if (t < NBINS) h[t] = 0;
    __syncthreads();
    int i = blockIdx.x * 256 + t;
    if (i < n) {
        int b = deg[i]; if (b > NBINS - 1) b = NBINS - 1;
        int r = atomicAdd(&h[b], 1);   // rank within (block, bin), LDS atomic
        perm[blockHist[b * NSB + blockIdx.x] + r] = i;
    }
}

// ---------------- prep: BN fold, W transpose->bf16, x->bf16 ----------------

__global__ void prep_bn(const float* __restrict__ gamma, const float* __restrict__ beta,
                        const float* __restrict__ mean, const float* __restrict__ var,
                        const float* __restrict__ b1,
                        float* __restrict__ colA, float* __restrict__ colB, int n) {
    int i = blockIdx.x * blockDim.x + threadIdx.x;
    if (i < n) {
        float A = gamma[i] * rsqrtf(var[i] + BN_EPS);
        colA[i] = A;
        colB[i] = beta[i] - mean[i] * A + b1[i] * A;
    }
}

// W[l][k][n] f32  ->  WT[l][n][k] bf16
__global__ void prep_wt(const float* __restrict__ W1, const float* __restrict__ W2,
                        unsigned short* __restrict__ W1T, unsigned short* __restrict__ W2T, int total) {
    int i = blockIdx.x * blockDim.x + threadIdx.x;
    if (i < total) {
        int l  = i / (DIM * DIM);
        int r  = i - l * DIM * DIM;
        int nn = r / DIM;
        int kk = r - nn * DIM;
        int sidx = l * DIM * DIM + kk * DIM + nn;
        W1T[i] = f2b(W1[sidx]);
        W2T[i] = f2b(W2[sidx]);
    }
}

__global__ void conv_x(const float* __restrict__ x, unsigned short* __restrict__ xb, int n4) {
    int i = blockIdx.x * blockDim.x + threadIdx.x;
    if (i < n4) {
        float4 v = ((const float4*)x)[i];
        unsigned lo = pack2(v.x, v.y);
        unsigned hi = pack2(v.z, v.w);
        ((uint2*)xb)[i] = make_uint2(lo, hi);
    }
}

// ---------------- gather0: weighted SimpleConv + supernode select (perm'd) ----------------
// 4 nodes/wave (degree-matched via perm), 16 lanes/node, 16B chunks, 8x unrolled.

__global__ __launch_bounds__(256) void gather0(const unsigned short* __restrict__ xb,
                                               const int* __restrict__ off, const int* __restrict__ deg,
                                               const unsigned* __restrict__ csr4,
                                               const int* __restrict__ snmask,
                                               const int* __restrict__ perm,
                                               unsigned short* __restrict__ X, int n) {
    int wave = (blockIdx.x * blockDim.x + threadIdx.x) >> 6;
    int lane = threadIdx.x & 63;
    int q    = lane >> 4;
    int l16  = lane & 15;
    int idx  = wave * 4 + q;
    bool valid = idx < n;
    int node = perm[valid ? idx : (n - 1)];
    int base = off[node];
    int dg   = valid ? deg[node] : 0;

    float acc[8];
#pragma unroll
    for (int i = 0; i < 8; ++i) acc[i] = 0.f;

    int j = 0;
    for (; j + 8 <= dg; j += 8) {
        unsigned cc[8];
#pragma unroll
        for (int u = 0; u < 8; ++u) cc[u] = csr4[base + j + u];
        bf16x8 vv[8];
#pragma unroll
        for (int u = 0; u < 8; ++u)
            vv[u] = *(const bf16x8*)&xb[(long)(cc[u] & 0xffffu) * DIM + l16 * 8];
#pragma unroll
        for (int u = 0; u < 8; ++u) {
            float w = __half2float(__ushort_as_half((unsigned short)(cc[u] >> 16)));
#pragma unroll
            for (int i = 0; i < 8; ++i) acc[i] = fmaf(w, b2f(vv[u][i]), acc[i]);
        }
    }
    for (; j + 4 <= dg; j += 4) {
        unsigned cc[4];
#pragma unroll
        for (int u = 0; u < 4; ++u) cc[u] = csr4[base + j + u];
        bf16x8 vv[4];
#pragma unroll
        for (int u = 0; u < 4; ++u)
            vv[u] = *(const bf16x8*)&xb[(long)(cc[u] & 0xffffu) * DIM + l16 * 8];
#pragma unroll
        for (int u = 0; u < 4; ++u) {
            float w = __half2float(__ushort_as_half((unsigned short)(cc[u] >> 16)));
#pragma unroll
            for (int i = 0; i < 8; ++i) acc[i] = fmaf(w, b2f(vv[u][i]), acc[i]);
        }
    }
    for (; j < dg; ++j) {
        unsigned c = csr4[base + j];
        float w = __half2float(__ushort_as_half((unsigned short)(c >> 16)));
        bf16x8 v = *(const bf16x8*)&xb[(long)(c & 0xffffu) * DIM + l16 * 8];
#pragma unroll
        for (int i = 0; i < 8; ++i) acc[i] = fmaf(w, b2f(v[i]), acc[i]);
    }

    if (valid) {
        bf16x8 res = *(const bf16x8*)&xb[(long)node * DIM + l16 * 8];  // self
        if (snmask[node]) {
#pragma unroll
            for (int i = 0; i < 8; ++i) res[i] = (short)f2b(acc[i]);
        }
        *(bf16x8*)&X[(long)node * DIM + l16 * 8] = res;
    }
}

// ---------------- fused GIN layer: gather(LDS) -> Lin1+BN+ReLU -> Lin2+ReLU ----------------
// 512 threads = 8 waves, 64 (perm'd) rows/block. perm only changes scheduling,
// per-node arithmetic/order unchanged -> output bit-identical to unpermuted.
#define HPITCH 136   // bf16 elems; 272B rows: 16B-aligned, 2-way LDS aliasing only

__global__ __launch_bounds__(512) void gin_layer(const unsigned short* __restrict__ Xin,
                                                 unsigned short* __restrict__ Xout,
                                                 const int* __restrict__ off, const int* __restrict__ deg,
                                                 const unsigned* __restrict__ csr4,
                                                 const int* __restrict__ perm,
                                                 const unsigned short* __restrict__ W1T,
                                                 const unsigned short* __restrict__ W2T,
                                                 const float* __restrict__ colA, const float* __restrict__ colB,
                                                 const float* __restrict__ b2, int n) {
    __shared__ unsigned short h_in[64 * HPITCH];
    __shared__ unsigned short h_t[64 * HPITCH];
    int t    = threadIdx.x;
    int wid  = t >> 6;
    int lane = t & 63;
    int q    = lane >> 4;
    int l16  = lane & 15;
    int lm   = lane & 15;
    int lk   = (lane >> 4) * 8;
    int wr   = wid >> 2;          // 0..1
    int wc   = wid & 3;           // 0..3
    int c0   = wc * 32;
    int row0 = blockIdx.x * 64;

    // ---- W1 B-fragments first: weight fetch overlaps gather latency ----
    bf16x8 b1[2][4];
#pragma unroll
    for (int cs = 0; cs < 2; ++cs)
#pragma unroll
        for (int ks = 0; ks < 4; ++ks) {
            int col = c0 + cs * 16 + lm;
            b1[cs][ks] = *(const bf16x8*)&W1T[col * DIM + ks * 32 + lk];
        }

    // ---- gather phase: GIN eps=0 agg into h_in (degree-matched quarter-waves) ----
#pragma unroll
    for (int rnd = 0; rnd < 2; ++rnd) {
        int lrow = wid * 8 + rnd * 4 + q;
        int idx  = row0 + lrow;
        bool valid = idx < n;
        int node = perm[valid ? idx : (n - 1)];
        int base = off[node];
        int dg   = valid ? deg[node] : 0;

        float acc[8];
        {
            bf16x8 self = *(const bf16x8*)&Xin[(long)node * DIM + l16 * 8];
#pragma unroll
            for (int i = 0; i < 8; ++i) acc[i] = b2f(self[i]);
        }
        int j = 0;
        for (; j + 8 <= dg; j += 8) {
            unsigned ee[8];
#pragma unroll
            for (int u = 0; u < 8; ++u) ee[u] = csr4[base + j + u];
            bf16x8 vv[8];
#pragma unroll
            for (int u = 0; u < 8; ++u)
                vv[u] = *(const bf16x8*)&Xin[(long)(ee[u] & 0xffffu) * DIM + l16 * 8];
#pragma unroll
            for (int u = 0; u < 8; ++u)
#pragma unroll
                for (int i = 0; i < 8; ++i) acc[i] += b2f(vv[u][i]);
        }
        for (; j + 4 <= dg; j += 4) {
            unsigned ee[4];
#pragma unroll
            for (int u = 0; u < 4; ++u) ee[u] = csr4[base + j + u];
            bf16x8 vv[4];
#pragma unroll
            for (int u = 0; u < 4; ++u)
                vv[u] = *(const bf16x8*)&Xin[(long)(ee[u] & 0xffffu) * DIM + l16 * 8];
#pragma unroll
            for (int u = 0; u < 4; ++u)
#pragma unroll
                for (int i = 0; i < 8; ++i) acc[i] += b2f(vv[u][i]);
        }
        for (; j < dg; ++j) {
            unsigned e = csr4[base + j];
            bf16x8 v = *(const bf16x8*)&Xin[(long)(e & 0xffffu) * DIM + l16 * 8];
#pragma unroll
            for (int i = 0; i < 8; ++i) acc[i] += b2f(v[i]);
        }
        bf16x8 r;
#pragma unroll
        for (int i = 0; i < 8; ++i) r[i] = valid ? (short)f2b(acc[i]) : (short)0;
        *(bf16x8*)&h_in[lrow * HPITCH + l16 * 8] = r;
    }
    __syncthreads();

    // ---- GEMM1 ----
    bf16x8 a[2][4];
#pragma unroll
    for (int rs = 0; rs < 2; ++rs)
#pragma unroll
        for (int ks = 0; ks < 4; ++ks)
            a[rs][ks] = *(const bf16x8*)&h_in[(wr * 32 + rs * 16 + lm) * HPITCH + ks * 32 + lk];

    f32x4 acc[2][2];
    f32x4 z = {0.f, 0.f, 0.f, 0.f};
#pragma unroll
    for (int rs = 0; rs < 2; ++rs)
#pragma unroll
        for (int cs = 0; cs < 2; ++cs) acc[rs][cs] = z;

#pragma unroll
    for (int ks = 0; ks < 4; ++ks)
#pragma unroll
        for (int rs = 0; rs < 2; ++rs)
#pragma unroll
            for (int cs = 0; cs < 2; ++cs)
                acc[rs][cs] = __builtin_amdgcn_mfma_f32_16x16x32_bf16(a[rs][ks], b1[cs][ks], acc[rs][cs], 0, 0, 0);

    // ---- epilogue 1: affine(BN)+ReLU -> h_t ----
#pragma unroll
    for (int rs = 0; rs < 2; ++rs)
#pragma unroll
        for (int cs = 0; cs < 2; ++cs) {
            int colv = c0 + cs * 16 + lm;
            float cA = colA[colv], cB = colB[colv];
            int rbase = wr * 32 + rs * 16 + (lane >> 4) * 4;
            f32x4 av = acc[rs][cs];
#pragma unroll
            for (int v = 0; v < 4; ++v) {
                float h = fmaxf(fmaf(av[v], cA, cB), 0.f);
                h_t[(rbase + v) * HPITCH + colv] = f2b(h);
            }
        }
    __syncthreads();

    // ---- GEMM2 ----
    bf16x8 a2[2][4];
#pragma unroll
    for (int rs = 0; rs < 2; ++rs)
#pragma unroll
        for (int ks = 0; ks < 4; ++ks)
            a2[rs][ks] = *(const bf16x8*)&h_t[(wr * 32 + rs * 16 + lm) * HPITCH + ks * 32 + lk];

    bf16x8 b2f_[2][4];
#pragma unroll
    for (int cs = 0; cs < 2; ++cs)
#pragma unroll
        for (int ks = 0; ks < 4; ++ks) {
            int col = c0 + cs * 16 + lm;
            b2f_[cs][ks] = *(const bf16x8*)&W2T[col * DIM + ks * 32 + lk];
        }

#pragma unroll
    for (int rs = 0; rs < 2; ++rs)
#pragma unroll
        for (int cs = 0; cs < 2; ++cs) acc[rs][cs] = z;

#pragma unroll
    for (int ks = 0; ks < 4; ++ks)
#pragma unroll
        for (int rs = 0; rs < 2; ++rs)
#pragma unroll
            for (int cs = 0; cs < 2; ++cs)
                acc[rs][cs] = __builtin_amdgcn_mfma_f32_16x16x32_bf16(a2[rs][ks], b2f_[cs][ks], acc[rs][cs], 0, 0, 0);

    __syncthreads();

    // ---- epilogue 2: +bias, ReLU -> h_t ----
#pragma unroll
    for (int rs = 0; rs < 2; ++rs)
#pragma unroll
        for (int cs = 0; cs < 2; ++cs) {
            int colv = c0 + cs * 16 + lm;
            float bb = b2[colv];
            int rbase = wr * 32 + rs * 16 + (lane >> 4) * 4;
            f32x4 av = acc[rs][cs];
#pragma unroll
            for (int v = 0; v < 4; ++v) {
                float h = fmaxf(av[v] + bb, 0.f);
                h_t[(rbase + v) * HPITCH + colv] = f2b(h);
            }
        }
    __syncthreads();

    // ---- copy-out: 64 rows scattered to Xout[perm[.]], 32B per thread within row ----
    {
        int row = t >> 3;
        int ch  = (t & 7) * 16;
        int gr  = row0 + row;
        if (gr < n) {
            int node = perm[gr];
            *(bf16x8*)&Xout[(long)node * DIM + ch]     = *(const bf16x8*)&h_t[row * HPITCH + ch];
            *(bf16x8*)&Xout[(long)node * DIM + ch + 8] = *(const bf16x8*)&h_t[row * HPITCH + ch + 8];
        }
    }
}

// ---------------- pool (batch sorted -> run-accumulate) ----------------

__global__ __launch_bounds__(128) void pool_kernel(const unsigned short* __restrict__ X,
                                                   const int* __restrict__ batch,
                                                   float* __restrict__ POOL, int n) {
    int c  = threadIdx.x;
    int n0 = blockIdx.x * 128;
    if (n0 >= n) return;
    int n1 = n0 + 128; if (n1 > n) n1 = n;
    int gcur = batch[n0];
    float acc = 0.f;
    for (int i = n0; i < n1; ++i) {
        int g = batch[i];
        if (g != gcur) {
            atomicAdd(&POOL[(long)gcur * DIM + c], acc);
            acc = 0.f; gcur = g;
        }
        acc += __uint_as_float(((unsigned)X[(long)i * DIM + c]) << 16);
    }
    atomicAdd(&POOL[(long)gcur * DIM + c], acc);
}

// ---------------- final head ----------------

__global__ __launch_bounds__(128) void final_mlp(const float* __restrict__ POOL,
                                                 const float* __restrict__ Wf1, const float* __restrict__ bf1,
                                                 const float* __restrict__ Wf2, const float* __restrict__ bf2,
                                                 float* __restrict__ out) {
    int g = blockIdx.x;
    int t = threadIdx.x;
    __shared__ float p[128];
    __shared__ float h[128];
    p[t] = POOL[(long)g * DIM + t];
    __syncthreads();
    float acc = bf1[t];
#pragma unroll 8
    for (int k = 0; k < DIM; ++k) acc = fmaf(p[k], Wf1[k * DIM + t], acc);
    h[t] = fmaxf(acc, 0.f);
    __syncthreads();
    if (t < NCLS) {
        float acc2 = bf2[t];
#pragma unroll 8
        for (int k = 0; k < DIM; ++k) acc2 = fmaf(h[k], Wf2[k * NCLS + t], acc2);
        out[(long)g * NCLS + t] = acc2;
    }
}

// ---------------- launch ----------------

extern "C" void kernel_launch(void* const* d_in, const int* in_sizes, int n_in,
                              void* d_out, int out_size, void* d_ws, size_t ws_size,
                              hipStream_t stream) {
    const float* x      = (const float*)d_in[0];
    const int*   ei     = (const int*)d_in[1];
    const int*   snmask = (const int*)d_in[2];
    const float* emask  = (const float*)d_in[3];
    const int*   batch  = (const int*)d_in[4];
    const float* Ws1    = (const float*)d_in[5];
    const float* bs1    = (const float*)d_in[6];
    const float* gamma  = (const float*)d_in[7];
    const float* beta   = (const float*)d_in[8];
    const float* mean   = (const float*)d_in[9];
    const float* var    = (const float*)d_in[10];
    const float* Ws2    = (const float*)d_in[11];
    const float* bs2    = (const float*)d_in[12];
    const float* Wf1    = (const float*)d_in[13];
    const float* bf1    = (const float*)d_in[14];
    const float* Wf2    = (const float*)d_in[15];
    const float* bf2    = (const float*)d_in[16];
    float* out = (float*)d_out;

    const int* srcp = ei;
    const int* dstp = ei + NEDGES;

    char* ws = (char*)d_ws;
    size_t o = 0;
    auto alloc = [&](size_t bytes) -> void* {
        void* p = ws + o;
        o = (o + bytes + 255) & ~(size_t)255;
        return p;
    };
    unsigned short* XB  = (unsigned short*)alloc((size_t)NNODES * DIM * 2);
    unsigned short* X   = (unsigned short*)alloc((size_t)NNODES * DIM * 2);
    unsigned short* H   = (unsigned short*)alloc((size_t)NNODES * DIM * 2);
    int*   deg     = (int*)alloc((size_t)NNODES * 4);
    int*   off     = (int*)alloc((size_t)NNODES * 4);
    int*   cursor  = (int*)alloc((size_t)NNODES * 4);
    int*   part    = (int*)alloc((size_t)NSB * 4);
    unsigned* csr4 = (unsigned*)alloc((size_t)NEDGES * 4);
    int*   blockHist = (int*)alloc((size_t)NBINS * NSB * 4);
    int*   perm    = (int*)alloc((size_t)NNODES * 4);
    float* colA    = (float*)alloc((size_t)NLAYERS * DIM * 4);
    float* colB    = (float*)alloc((size_t)NLAYERS * DIM * 4);
    unsigned short* W1T = (unsigned short*)alloc((size_t)NLAYERS * DIM * DIM * 2);
    unsigned short* W2T = (unsigned short*)alloc((size_t)NLAYERS * DIM * DIM * 2);
    float* POOL    = (float*)alloc((size_t)NGRAPH * DIM * 4);

    // deg: 12500 int4; POOL: 8192 int4
    zero_bufs<<<(12500 + 255) / 256, 256, 0, stream>>>((int4*)deg, 12500, (int4*)POOL, 8192);

    count_deg<<<(NEDGES + 255) / 256, 256, 0, stream>>>(dstp, deg, NEDGES);
    partial_sum<<<NSB, SCAN_BLK, 0, stream>>>(deg, part, NNODES);
    scan_partials<<<1, 256, 0, stream>>>(part, NSB);
    emit_offsets<<<NSB, SCAN_BLK, 0, stream>>>(deg, part, off, cursor, NNODES);
    fill_csr<<<(NEDGES + 255) / 256, 256, 0, stream>>>(srcp, dstp, emask, cursor, csr4, NEDGES);
    hist_block<<<NSB, 256, 0, stream>>>(deg, blockHist, NNODES);
    scan_matrix<<<1, 1024, 0, stream>>>(blockHist, NBINS * NSB);
    place_block<<<NSB, 256, 0, stream>>>(deg, blockHist, perm, NNODES);
    prep_bn<<<(NLAYERS * DIM + 255) / 256, 256, 0, stream>>>(gamma, beta, mean, var, bs1, colA, colB, NLAYERS * DIM);
    prep_wt<<<(NLAYERS * DIM * DIM + 255) / 256, 256, 0, stream>>>(Ws1, Ws2, W1T, W2T, NLAYERS * DIM * DIM);
    conv_x<<<(NNODES * DIM / 4 + 255) / 256, 256, 0, stream>>>(x, XB, NNODES * DIM / 4);

    const int nWaves = (NNODES + 3) / 4;
    const int gatherBlocks = (nWaves * 64 + 255) / 256;
    gather0<<<gatherBlocks, 256, 0, stream>>>(XB, off, deg, csr4, snmask, perm, X, NNODES);

    // ping-pong: X -> H -> X -> H
    const unsigned short* bufs[4] = {X, H, X, H};
    const int layerBlocks = (NNODES + 63) / 64;
    for (int l = 0; l < NLAYERS; ++l) {
        gin_layer<<<layerBlocks, 512, 0, stream>>>((const unsigned short*)bufs[l],
                                                   (unsigned short*)bufs[l + 1],
                                                   off, deg, csr4, perm,
                                                   W1T + (size_t)l * DIM * DIM,
                                                   W2T + (size_t)l * DIM * DIM,
                                                   colA + (size_t)l * DIM,
                                                   colB + (size_t)l * DIM,
                                                   bs2 + (size_t)l * DIM, NNODES);
    }

    pool_kernel<<<(NNODES + 127) / 128, 128, 0, stream>>>(H, batch, POOL, NNODES);
    final_mlp<<<NGRAPH, 128, 0, stream>>>(POOL, Wf1, bf1, Wf2, bf2, out);
}

// Round 11
// 277.777 us; speedup vs baseline: 2.1704x; 1.0698x over previous
//
#include <hip/hip_runtime.h>
#include <hip/hip_bf16.h>
#include <hip/hip_fp16.h>

#define NNODES 50000
#define NEDGES 600000
#define DIM    128
#define NLAYERS 3
#define NCLS   10
#define NGRAPH 256
#define BN_EPS 1e-5f

#define SCAN_BLK 256
#define NSB ((NNODES + SCAN_BLK - 1) / SCAN_BLK)   // 196 blocks
#define NBINS 64

typedef __attribute__((ext_vector_type(8))) short bf16x8;   // 8 bf16 = 4 VGPR
typedef __attribute__((ext_vector_type(4))) float f32x4;

static __device__ __forceinline__ unsigned short f2b(float f) {
    union { __hip_bfloat16 h; unsigned short u; } c;
    c.h = __float2bfloat16(f);
    return c.u;
}
static __device__ __forceinline__ float b2f(short s) {
    return __uint_as_float(((unsigned)(unsigned short)s) << 16);
}
static __device__ __forceinline__ unsigned pack2(float a, float b) {
    return (unsigned)f2b(a) | ((unsigned)f2b(b) << 16);
}

// ---------------- workspace zeroing ----------------
__global__ __launch_bounds__(256) void zero_bufs(int4* __restrict__ a, int na,
                                                 int4* __restrict__ b, int nb) {
    int i = blockIdx.x * 256 + threadIdx.x;
    int4 z = make_int4(0, 0, 0, 0);
    if (i < na) a[i] = z;
    if (i < nb) b[i] = z;
}

// ---------------- CSR build ----------------
// count + per-edge rank in one atomic pass (round-10 lesson: the dependent
// atomic in fill_csr cost 42us; rank store is coalesced and frees placement
// to be a pure scatter).
__global__ void count_deg(const int* __restrict__ dst, int* __restrict__ deg,
                          int* __restrict__ rank, int E) {
    int e = blockIdx.x * blockDim.x + threadIdx.x;
    if (e < E) rank[e] = atomicAdd(&deg[dst[e]], 1);
}

__global__ __launch_bounds__(SCAN_BLK) void partial_sum(const int* __restrict__ deg,
                                                        int* __restrict__ part, int n) {
    int t = threadIdx.x;
    int i = blockIdx.x * SCAN_BLK + t;
    int v = (i < n) ? deg[i] : 0;
#pragma unroll
    for (int o = 32; o > 0; o >>= 1) v += __shfl_down(v, o, 64);
    __shared__ int s[SCAN_BLK / 64];
    if ((t & 63) == 0) s[t >> 6] = v;
    __syncthreads();
    if (t == 0) {
        int sum = 0;
#pragma unroll
        for (int w = 0; w < SCAN_BLK / 64; ++w) sum += s[w];
        part[blockIdx.x] = sum;
    }
}

__global__ __launch_bounds__(256) void scan_partials(int* __restrict__ part, int nb) {
    __shared__ int s[256];
    int t = threadIdx.x;
    int v = (t < nb) ? part[t] : 0;
    s[t] = v;
    __syncthreads();
    for (int o = 1; o < 256; o <<= 1) {
        int u = (t >= o) ? s[t - o] : 0;
        __syncthreads();
        s[t] += u;
        __syncthreads();
    }
    if (t < nb) part[t] = (t == 0) ? 0 : s[t - 1];
}

__global__ __launch_bounds__(SCAN_BLK) void emit_offsets(const int* __restrict__ deg,
                                                         const int* __restrict__ part,
                                                         int* __restrict__ off, int n) {
    __shared__ int s[SCAN_BLK];
    int t = threadIdx.x;
    int i = blockIdx.x * SCAN_BLK + t;
    int v = (i < n) ? deg[i] : 0;
    s[t] = v;
    __syncthreads();
    for (int o = 1; o < SCAN_BLK; o <<= 1) {
        int u = (t >= o) ? s[t - o] : 0;
        __syncthreads();
        s[t] += u;
        __syncthreads();
    }
    if (i < n) off[i] = part[blockIdx.x] + s[t] - v;
}

// pure scatter, no atomics: 4B per edge (low16 src, high16 f16 weight)
__global__ void place_csr(const int* __restrict__ src, const int* __restrict__ dst,
                          const float* __restrict__ emask,
                          const int* __restrict__ off, const int* __restrict__ rank,
                          unsigned* __restrict__ csr4, int E) {
    int e = blockIdx.x * blockDim.x + threadIdx.x;
    if (e < E) {
        int d = dst[e];
        unsigned wbits = (unsigned)__half_as_ushort(__float2half(emask[e]));
        csr4[off[d] + rank[e]] = (unsigned)src[e] | (wbits << 16);
    }
}

// ---------------- degree-balanced permutation: contention-free counting sort ----------------

__global__ __launch_bounds__(256) void hist_block(const int* __restrict__ deg,
                                                  int* __restrict__ blockHist, int n) {
    __shared__ int h[NBINS];
    int t = threadIdx.x;
    if (t < NBINS) h[t] = 0;
    __syncthreads();
    int i = blockIdx.x * 256 + t;
    if (i < n) {
        int b = deg[i]; if (b > NBINS - 1) b = NBINS - 1;
        atomicAdd(&h[b], 1);       // LDS atomic
    }
    __syncthreads();
    if (t < NBINS) blockHist[t * NSB + blockIdx.x] = h[t];   // bin-major
}

__global__ __launch_bounds__(1024) void scan_matrix(int* __restrict__ m, int total) {
    __shared__ int s[1024];
    int t = threadIdx.x;
    const int CH = (total + 1023) / 1024;   // 13
    int lo = t * CH;
    int hi = lo + CH; if (hi > total) hi = total;
    int sum = 0;
    for (int i = lo; i < hi; ++i) sum += m[i];
    s[t] = sum;
    __syncthreads();
    for (int o = 1; o < 1024; o <<= 1) {
        int v = (t >= o) ? s[t - o] : 0;
        __syncthreads();
        s[t] += v;
        __syncthreads();
    }
    int run = (t == 0) ? 0 : s[t - 1];
    for (int i = lo; i < hi; ++i) {
        int v = m[i]; m[i] = run; run += v;
    }
}

__global__ __launch_bounds__(256) void place_block(const int* __restrict__ deg,
                                                   const int* __restrict__ blockHist,
                                                   int* __restrict__ perm, int n) {
    __shared__ int h[NBINS];
    int t = threadIdx.x;
    if (t < NBINS) h[t] = 0;
    __syncthreads();
    int i = blockIdx.x * 256 + t;
    if (i < n) {
        int b = deg[i]; if (b > NBINS - 1) b = NBINS - 1;
        int r = atomicAdd(&h[b], 1);   // LDS rank within (block, bin)
        perm[blockHist[b * NSB + blockIdx.x] + r] = i;
    }
}

// ---------------- prep: BN fold, W transpose->bf16, x->bf16 ----------------

__global__ void prep_bn(const float* __restrict__ gamma, const float* __restrict__ beta,
                        const float* __restrict__ mean, const float* __restrict__ var,
                        const float* __restrict__ b1,
                        float* __restrict__ colA, float* __restrict__ colB, int n) {
    int i = blockIdx.x * blockDim.x + threadIdx.x;
    if (i < n) {
        float A = gamma[i] * rsqrtf(var[i] + BN_EPS);
        colA[i] = A;
        colB[i] = beta[i] - mean[i] * A + b1[i] * A;
    }
}

// W[l][k][n] f32  ->  WT[l][n][k] bf16
__global__ void prep_wt(const float* __restrict__ W1, const float* __restrict__ W2,
                        unsigned short* __restrict__ W1T, unsigned short* __restrict__ W2T, int total) {
    int i = blockIdx.x * blockDim.x + threadIdx.x;
    if (i < total) {
        int l  = i / (DIM * DIM);
        int r  = i - l * DIM * DIM;
        int nn = r / DIM;
        int kk = r - nn * DIM;
        int sidx = l * DIM * DIM + kk * DIM + nn;
        W1T[i] = f2b(W1[sidx]);
        W2T[i] = f2b(W2[sidx]);
    }
}

__global__ void conv_x(const float* __restrict__ x, unsigned short* __restrict__ xb, int n4) {
    int i = blockIdx.x * blockDim.x + threadIdx.x;
    if (i < n4) {
        float4 v = ((const float4*)x)[i];
        unsigned lo = pack2(v.x, v.y);
        unsigned hi = pack2(v.z, v.w);
        ((uint2*)xb)[i] = make_uint2(lo, hi);
    }
}

// ---------------- gather0: weighted SimpleConv + supernode select (perm'd) ----------------

__global__ __launch_bounds__(256) void gather0(const unsigned short* __restrict__ xb,
                                               const int* __restrict__ off, const int* __restrict__ deg,
                                               const unsigned* __restrict__ csr4,
                                               const int* __restrict__ snmask,
                                               const int* __restrict__ perm,
                                               unsigned short* __restrict__ X, int n) {
    int wave = (blockIdx.x * blockDim.x + threadIdx.x) >> 6;
    int lane = threadIdx.x & 63;
    int q    = lane >> 4;
    int l16  = lane & 15;
    int idx  = wave * 4 + q;
    bool valid = idx < n;
    int node = perm[valid ? idx : (n - 1)];
    int base = off[node];
    int dg   = valid ? deg[node] : 0;

    float acc[8];
#pragma unroll
    for (int i = 0; i < 8; ++i) acc[i] = 0.f;

    int j = 0;
    for (; j + 8 <= dg; j += 8) {
        unsigned cc[8];
#pragma unroll
        for (int u = 0; u < 8; ++u) cc[u] = csr4[base + j + u];
        bf16x8 vv[8];
#pragma unroll
        for (int u = 0; u < 8; ++u)
            vv[u] = *(const bf16x8*)&xb[(long)(cc[u] & 0xffffu) * DIM + l16 * 8];
#pragma unroll
        for (int u = 0; u < 8; ++u) {
            float w = __half2float(__ushort_as_half((unsigned short)(cc[u] >> 16)));
#pragma unroll
            for (int i = 0; i < 8; ++i) acc[i] = fmaf(w, b2f(vv[u][i]), acc[i]);
        }
    }
    for (; j + 4 <= dg; j += 4) {
        unsigned cc[4];
#pragma unroll
        for (int u = 0; u < 4; ++u) cc[u] = csr4[base + j + u];
        bf16x8 vv[4];
#pragma unroll
        for (int u = 0; u < 4; ++u)
            vv[u] = *(const bf16x8*)&xb[(long)(cc[u] & 0xffffu) * DIM + l16 * 8];
#pragma unroll
        for (int u = 0; u < 4; ++u) {
            float w = __half2float(__ushort_as_half((unsigned short)(cc[u] >> 16)));
#pragma unroll
            for (int i = 0; i < 8; ++i) acc[i] = fmaf(w, b2f(vv[u][i]), acc[i]);
        }
    }
    for (; j < dg; ++j) {
        unsigned c = csr4[base + j];
        float w = __half2float(__ushort_as_half((unsigned short)(c >> 16)));
        bf16x8 v = *(const bf16x8*)&xb[(long)(c & 0xffffu) * DIM + l16 * 8];
#pragma unroll
        for (int i = 0; i < 8; ++i) acc[i] = fmaf(w, b2f(v[i]), acc[i]);
    }

    if (valid) {
        bf16x8 res = *(const bf16x8*)&xb[(long)node * DIM + l16 * 8];  // self
        if (snmask[node]) {
#pragma unroll
            for (int i = 0; i < 8; ++i) res[i] = (short)f2b(acc[i]);
        }
        *(bf16x8*)&X[(long)node * DIM + l16 * 8] = res;
    }
}

// ---------------- fused GIN layer: gather(LDS) -> Lin1+BN+ReLU -> Lin2+ReLU ----------------
// 512 threads = 8 waves, 64 rows/block. DEALT group mapping: LDS group lg (0..15)
// of block b takes sorted quarter-wave group lg*gridDim.x + b -> every block gets a
// stratified degree sample (balanced block runtimes; round-10's sorted blocks made
// the heavy blocks a low-occupancy tail). Row-independent math -> output unchanged.
#define HPITCH 136   // bf16 elems; 272B rows: 16B-aligned, 2-way LDS aliasing only

__global__ __launch_bounds__(512) void gin_layer(const unsigned short* __restrict__ Xin,
                                                 unsigned short* __restrict__ Xout,
                                                 const int* __restrict__ off, const int* __restrict__ deg,
                                                 const unsigned* __restrict__ csr4,
                                                 const int* __restrict__ perm,
                                                 const unsigned short* __restrict__ W1T,
                                                 const unsigned short* __restrict__ W2T,
                                                 const float* __restrict__ colA, const float* __restrict__ colB,
                                                 const float* __restrict__ b2, int n) {
    __shared__ unsigned short h_in[64 * HPITCH];
    __shared__ unsigned short h_t[64 * HPITCH];
    int t    = threadIdx.x;
    int wid  = t >> 6;
    int lane = t & 63;
    int q    = lane >> 4;
    int l16  = lane & 15;
    int lm   = lane & 15;
    int lk   = (lane >> 4) * 8;
    int wr   = wid >> 2;          // 0..1
    int wc   = wid & 3;           // 0..3
    int c0   = wc * 32;
    int nb   = gridDim.x;

    // ---- W1 B-fragments first: weight fetch overlaps gather latency ----
    bf16x8 b1[2][4];
#pragma unroll
    for (int cs = 0; cs < 2; ++cs)
#pragma unroll
        for (int ks = 0; ks < 4; ++ks) {
            int col = c0 + cs * 16 + lm;
            b1[cs][ks] = *(const bf16x8*)&W1T[col * DIM + ks * 32 + lk];
        }

    // ---- gather phase: GIN eps=0 agg into h_in (dealt, degree-matched quarter-waves) ----
#pragma unroll
    for (int rnd = 0; rnd < 2; ++rnd) {
        int lrow = wid * 8 + rnd * 4 + q;
        int lg   = lrow >> 2;                       // 0..15
        int idx  = (lg * nb + blockIdx.x) * 4 + q;  // dealt group, sorted-adjacent within
        bool valid = idx < n;
        int node = perm[valid ? idx : (n - 1)];
        int base = off[node];
        int dg   = valid ? deg[node] : 0;

        float acc[8];
        {
            bf16x8 self = *(const bf16x8*)&Xin[(long)node * DIM + l16 * 8];
#pragma unroll
            for (int i = 0; i < 8; ++i) acc[i] = b2f(self[i]);
        }
        int j = 0;
        for (; j + 8 <= dg; j += 8) {
            unsigned ee[8];
#pragma unroll
            for (int u = 0; u < 8; ++u) ee[u] = csr4[base + j + u];
            bf16x8 vv[8];
#pragma unroll
            for (int u = 0; u < 8; ++u)
                vv[u] = *(const bf16x8*)&Xin[(long)(ee[u] & 0xffffu) * DIM + l16 * 8];
#pragma unroll
            for (int u = 0; u < 8; ++u)
#pragma unroll
                for (int i = 0; i < 8; ++i) acc[i] += b2f(vv[u][i]);
        }
        for (; j + 4 <= dg; j += 4) {
            unsigned ee[4];
#pragma unroll
            for (int u = 0; u < 4; ++u) ee[u] = csr4[base + j + u];
            bf16x8 vv[4];
#pragma unroll
            for (int u = 0; u < 4; ++u)
                vv[u] = *(const bf16x8*)&Xin[(long)(ee[u] & 0xffffu) * DIM + l16 * 8];
#pragma unroll
            for (int u = 0; u < 4; ++u)
#pragma unroll
                for (int i = 0; i < 8; ++i) acc[i] += b2f(vv[u][i]);
        }
        for (; j < dg; ++j) {
            unsigned e = csr4[base + j];
            bf16x8 v = *(const bf16x8*)&Xin[(long)(e & 0xffffu) * DIM + l16 * 8];
#pragma unroll
            for (int i = 0; i < 8; ++i) acc[i] += b2f(v[i]);
        }
        bf16x8 r;
#pragma unroll
        for (int i = 0; i < 8; ++i) r[i] = valid ? (short)f2b(acc[i]) : (short)0;
        *(bf16x8*)&h_in[lrow * HPITCH + l16 * 8] = r;
    }
    __syncthreads();

    // ---- GEMM1 ----
    bf16x8 a[2][4];
#pragma unroll
    for (int rs = 0; rs < 2; ++rs)
#pragma unroll
        for (int ks = 0; ks < 4; ++ks)
            a[rs][ks] = *(const bf16x8*)&h_in[(wr * 32 + rs * 16 + lm) * HPITCH + ks * 32 + lk];

    f32x4 acc[2][2];
    f32x4 z = {0.f, 0.f, 0.f, 0.f};
#pragma unroll
    for (int rs = 0; rs < 2; ++rs)
#pragma unroll
        for (int cs = 0; cs < 2; ++cs) acc[rs][cs] = z;

#pragma unroll
    for (int ks = 0; ks < 4; ++ks)
#pragma unroll
        for (int rs = 0; rs < 2; ++rs)
#pragma unroll
            for (int cs = 0; cs < 2; ++cs)
                acc[rs][cs] = __builtin_amdgcn_mfma_f32_16x16x32_bf16(a[rs][ks], b1[cs][ks], acc[rs][cs], 0, 0, 0);

    // ---- epilogue 1: affine(BN)+ReLU -> h_t ----
#pragma unroll
    for (int rs = 0; rs < 2; ++rs)
#pragma unroll
        for (int cs = 0; cs < 2; ++cs) {
            int colv = c0 + cs * 16 + lm;
            float cA = colA[colv], cB = colB[colv];
            int rbase = wr * 32 + rs * 16 + (lane >> 4) * 4;
            f32x4 av = acc[rs][cs];
#pragma unroll
            for (int v = 0; v < 4; ++v) {
                float h = fmaxf(fmaf(av[v], cA, cB), 0.f);
                h_t[(rbase + v) * HPITCH + colv] = f2b(h);
            }
        }
    __syncthreads();

    // ---- GEMM2 ----
    bf16x8 a2[2][4];
#pragma unroll
    for (int rs = 0; rs < 2; ++rs)
#pragma unroll
        for (int ks = 0; ks < 4; ++ks)
            a2[rs][ks] = *(const bf16x8*)&h_t[(wr * 32 + rs * 16 + lm) * HPITCH + ks * 32 + lk];

    bf16x8 b2f_[2][4];
#pragma unroll
    for (int cs = 0; cs < 2; ++cs)
#pragma unroll
        for (int ks = 0; ks < 4; ++ks) {
            int col = c0 + cs * 16 + lm;
            b2f_[cs][ks] = *(const bf16x8*)&W2T[col * DIM + ks * 32 + lk];
        }

#pragma unroll
    for (int rs = 0; rs < 2; ++rs)
#pragma unroll
        for (int cs = 0; cs < 2; ++cs) acc[rs][cs] = z;

#pragma unroll
    for (int ks = 0; ks < 4; ++ks)
#pragma unroll
        for (int rs = 0; rs < 2; ++rs)
#pragma unroll
            for (int cs = 0; cs < 2; ++cs)
                acc[rs][cs] = __builtin_amdgcn_mfma_f32_16x16x32_bf16(a2[rs][ks], b2f_[cs][ks], acc[rs][cs], 0, 0, 0);

    __syncthreads();

    // ---- epilogue 2: +bias, ReLU -> h_t ----
#pragma unroll
    for (int rs = 0; rs < 2; ++rs)
#pragma unroll
        for (int cs = 0; cs < 2; ++cs) {
            int colv = c0 + cs * 16 + lm;
            float bb = b2[colv];
            int rbase = wr * 32 + rs * 16 + (lane >> 4) * 4;
            f32x4 av = acc[rs][cs];
#pragma unroll
            for (int v = 0; v < 4; ++v) {
                float h = fmaxf(av[v] + bb, 0.f);
                h_t[(rbase + v) * HPITCH + colv] = f2b(h);
            }
        }
    __syncthreads();

    // ---- copy-out: row -> dealt idx -> Xout[perm[idx]], 32B per thread ----
    {
        int row = t >> 3;
        int ch  = (t & 7) * 16;
        int idx = ((row >> 2) * nb + blockIdx.x) * 4 + (row & 3);
        if (idx < n) {
            int node = perm[idx];
            *(bf16x8*)&Xout[(long)node * DIM + ch]     = *(const bf16x8*)&h_t[row * HPITCH + ch];
            *(bf16x8*)&Xout[(long)node * DIM + ch + 8] = *(const bf16x8*)&h_t[row * HPITCH + ch + 8];
        }
    }
}

// ---------------- pool (batch sorted -> run-accumulate) ----------------

__global__ __launch_bounds__(128) void pool_kernel(const unsigned short* __restrict__ X,
                                                   const int* __restrict__ batch,
                                                   float* __restrict__ POOL, int n) {
    int c  = threadIdx.x;
    int n0 = blockIdx.x * 128;
    if (n0 >= n) return;
    int n1 = n0 + 128; if (n1 > n) n1 = n;
    int gcur = batch[n0];
    float acc = 0.f;
    for (int i = n0; i < n1; ++i) {
        int g = batch[i];
        if (g != gcur) {
            atomicAdd(&POOL[(long)gcur * DIM + c], acc);
            acc = 0.f; gcur = g;
        }
        acc += __uint_as_float(((unsigned)X[(long)i * DIM + c]) << 16);
    }
    atomicAdd(&POOL[(long)gcur * DIM + c], acc);
}

// ---------------- final head ----------------

__global__ __launch_bounds__(128) void final_mlp(const float* __restrict__ POOL,
                                                 const float* __restrict__ Wf1, const float* __restrict__ bf1,
                                                 const float* __restrict__ Wf2, const float* __restrict__ bf2,
                                                 float* __restrict__ out) {
    int g = blockIdx.x;
    int t = threadIdx.x;
    __shared__ float p[128];
    __shared__ float h[128];
    p[t] = POOL[(long)g * DIM + t];
    __syncthreads();
    float acc = bf1[t];
#pragma unroll 8
    for (int k = 0; k < DIM; ++k) acc = fmaf(p[k], Wf1[k * DIM + t], acc);
    h[t] = fmaxf(acc, 0.f);
    __syncthreads();
    if (t < NCLS) {
        float acc2 = bf2[t];
#pragma unroll 8
        for (int k = 0; k < DIM; ++k) acc2 = fmaf(h[k], Wf2[k * NCLS + t], acc2);
        out[(long)g * NCLS + t] = acc2;
    }
}

// ---------------- launch ----------------

extern "C" void kernel_launch(void* const* d_in, const int* in_sizes, int n_in,
                              void* d_out, int out_size, void* d_ws, size_t ws_size,
                              hipStream_t stream) {
    const float* x      = (const float*)d_in[0];
    const int*   ei     = (const int*)d_in[1];
    const int*   snmask = (const int*)d_in[2];
    const float* emask  = (const float*)d_in[3];
    const int*   batch  = (const int*)d_in[4];
    const float* Ws1    = (const float*)d_in[5];
    const float* bs1    = (const float*)d_in[6];
    const float* gamma  = (const float*)d_in[7];
    const float* beta   = (const float*)d_in[8];
    const float* mean   = (const float*)d_in[9];
    const float* var    = (const float*)d_in[10];
    const float* Ws2    = (const float*)d_in[11];
    const float* bs2    = (const float*)d_in[12];
    const float* Wf1    = (const float*)d_in[13];
    const float* bf1    = (const float*)d_in[14];
    const float* Wf2    = (const float*)d_in[15];
    const float* bf2    = (const float*)d_in[16];
    float* out = (float*)d_out;

    const int* srcp = ei;
    const int* dstp = ei + NEDGES;

    char* ws = (char*)d_ws;
    size_t o = 0;
    auto alloc = [&](size_t bytes) -> void* {
        void* p = ws + o;
        o = (o + bytes + 255) & ~(size_t)255;
        return p;
    };
    unsigned short* XB  = (unsigned short*)alloc((size_t)NNODES * DIM * 2);
    unsigned short* X   = (unsigned short*)alloc((size_t)NNODES * DIM * 2);
    unsigned short* H   = (unsigned short*)alloc((size_t)NNODES * DIM * 2);
    int*   deg     = (int*)alloc((size_t)NNODES * 4);
    int*   off     = (int*)alloc((size_t)NNODES * 4);
    int*   rank    = (int*)alloc((size_t)NEDGES * 4);
    int*   part    = (int*)alloc((size_t)NSB * 4);
    unsigned* csr4 = (unsigned*)alloc((size_t)NEDGES * 4);
    int*   blockHist = (int*)alloc((size_t)NBINS * NSB * 4);
    int*   perm    = (int*)alloc((size_t)NNODES * 4);
    float* colA    = (float*)alloc((size_t)NLAYERS * DIM * 4);
    float* colB    = (float*)alloc((size_t)NLAYERS * DIM * 4);
    unsigned short* W1T = (unsigned short*)alloc((size_t)NLAYERS * DIM * DIM * 2);
    unsigned short* W2T = (unsigned short*)alloc((size_t)NLAYERS * DIM * DIM * 2);
    float* POOL    = (float*)alloc((size_t)NGRAPH * DIM * 4);

    // deg: 12500 int4; POOL: 8192 int4
    zero_bufs<<<(12500 + 255) / 256, 256, 0, stream>>>((int4*)deg, 12500, (int4*)POOL, 8192);

    count_deg<<<(NEDGES + 255) / 256, 256, 0, stream>>>(dstp, deg, rank, NEDGES);
    partial_sum<<<NSB, SCAN_BLK, 0, stream>>>(deg, part, NNODES);
    scan_partials<<<1, 256, 0, stream>>>(part, NSB);
    emit_offsets<<<NSB, SCAN_BLK, 0, stream>>>(deg, part, off, NNODES);
    place_csr<<<(NEDGES + 255) / 256, 256, 0, stream>>>(srcp, dstp, emask, off, rank, csr4, NEDGES);
    hist_block<<<NSB, 256, 0, stream>>>(deg, blockHist, NNODES);
    scan_matrix<<<1, 1024, 0, stream>>>(blockHist, NBINS * NSB);
    place_block<<<NSB, 256, 0, stream>>>(deg, blockHist, perm, NNODES);
    prep_bn<<<(NLAYERS * DIM + 255) / 256, 256, 0, stream>>>(gamma, beta, mean, var, bs1, colA, colB, NLAYERS * DIM);
    prep_wt<<<(NLAYERS * DIM * DIM + 255) / 256, 256, 0, stream>>>(Ws1, Ws2, W1T, W2T, NLAYERS * DIM * DIM);
    conv_x<<<(NNODES * DIM / 4 + 255) / 256, 256, 0, stream>>>(x, XB, NNODES * DIM / 4);

    const int nWaves = (NNODES + 3) / 4;
    const int gatherBlocks = (nWaves * 64 + 255) / 256;
    gather0<<<gatherBlocks, 256, 0, stream>>>(XB, off, deg, csr4, snmask, perm, X, NNODES);

    // ping-pong: X -> H -> X -> H
    const unsigned short* bufs[4] = {X, H, X, H};
    const int layerBlocks = (NNODES + 63) / 64;
    for (int l = 0; l < NLAYERS; ++l) {
        gin_layer<<<layerBlocks, 512, 0, stream>>>((const unsigned short*)bufs[l],
                                                   (unsigned short*)bufs[l + 1],
                                                   off, deg, csr4, perm,
                                                   W1T + (size_t)l * DIM * DIM,
                                                   W2T + (size_t)l * DIM * DIM,
                                                   colA + (size_t)l * DIM,
                                                   colB + (size_t)l * DIM,
                                                   bs2 + (size_t)l * DIM, NNODES);
    }

    pool_kernel<<<(NNODES + 127) / 128, 128, 0, stream>>>(H, batch, POOL, NNODES);
    final_mlp<<<NGRAPH, 128, 0, stream>>>(POOL, Wf1, bf1, Wf2, bf2, out);
}